// Round 4
// baseline (456.955 us; speedup 1.0000x reference)
//
#include <hip/hip_runtime.h>
#include <hip/hip_bf16.h>
#include <stdint.h>

// Problem constants
#define B_   32
#define N_   480
#define DIM_ 1024
#define H_   16
#define D_   64
#define M_   (B_*N_)   // 15360
#define BH_  (B_*H_)   // 512

typedef __bf16 bf16;
typedef __bf16 bf16x4 __attribute__((ext_vector_type(4)));
typedef __bf16 bf16x8 __attribute__((ext_vector_type(8)));
typedef short  short4v __attribute__((ext_vector_type(4)));
typedef float  f32x4  __attribute__((ext_vector_type(4)));

// async global->LDS, 16B per lane; LDS dest = wave-uniform base + lane*16
__device__ __forceinline__ void gld_lds16(const void* g, void* l) {
    using GP = const __attribute__((address_space(1))) unsigned int*;
    using LP = __attribute__((address_space(3))) unsigned int*;
    __builtin_amdgcn_global_load_lds((GP)(uintptr_t)g, (LP)(unsigned int)(uintptr_t)l, 16, 0, 0);
}

// ---------------- fp32 -> bf16 converts ----------------
__global__ void cvt4(const float* __restrict__ in, bf16* __restrict__ out, int n4) {
    int i = blockIdx.x * 256 + threadIdx.x;
    if (i >= n4) return;
    float4 v = ((const float4*)in)[i];
    bf16x4 o = { (bf16)v.x, (bf16)v.y, (bf16)v.z, (bf16)v.w };
    ((bf16x4*)out)[i] = o;
}

__global__ void cvtW(const float* __restrict__ Wq, const float* __restrict__ Wk,
                     const float* __restrict__ Wv, const float* __restrict__ Wo,
                     bf16* __restrict__ Wcat, bf16* __restrict__ Wob) {
    int i = blockIdx.x * 256 + threadIdx.x;
    const float* src; bf16* dst;
    switch (blockIdx.y) {
        case 0: src = Wq; dst = Wcat;                break;
        case 1: src = Wk; dst = Wcat + DIM_*DIM_;    break;
        case 2: src = Wv; dst = Wcat + 2*DIM_*DIM_;  break;
        default: src = Wo; dst = Wob;                break;
    }
    float4 v = ((const float4*)src)[i];
    bf16x4 o = { (bf16)v.x, (bf16)v.y, (bf16)v.z, (bf16)v.w };
    ((bf16x4*)dst)[i] = o;
}

// ======== shared GEMM core: 128x128 tile, BK=64, XOR-swizzled LDS ========
#define GEMM_PRE()                                                            \
    const int tid  = threadIdx.x;                                             \
    const int lane = tid & 63;                                                \
    const int wid  = tid >> 6;                                                \
    const int wm   = wid & 1, wn = wid >> 1;                                  \
    const int m0   = blockIdx.y * 128;                                        \
    const int n0   = blockIdx.x * 128;                                        \
    const int lm   = lane & 15, lq = lane >> 4;                               \
    const int aLane = (lane >> 3) * 1024 + (((lane & 7) ^ (lane >> 3)) & 7) * 8; \
    const bf16* Asrc = A  + (m0 + wid*32) * 1024 + aLane;                     \
    const bf16* Bsrc = Bw + (n0 + wid*32) * 1024 + aLane;                     \
    bf16* AsDst = As + (wid*32)*64;                                           \
    bf16* BsDst = Bs + (wid*32)*64;                                           \
    int rowA[4], rowB[4];                                                     \
    _Pragma("unroll") for (int m = 0; m < 4; ++m) rowA[m] = (wm*64 + m*16 + lm)*64; \
    _Pragma("unroll") for (int n = 0; n < 4; ++n) rowB[n] = (wn*64 + n*16 + lm)*64; \
    const int sw = lm & 7;                                                    \
    int phys[2];                                                              \
    phys[0] = ((lq)     ^ sw) * 8;                                            \
    phys[1] = ((4 + lq) ^ sw) * 8;

#define GEMM_KLOOP(FIRST, SECOND)                                             \
    for (int k0 = 0; k0 < 1024; k0 += 64) {                                   \
        _Pragma("unroll") for (int j = 0; j < 4; ++j) {                       \
            gld_lds16(Asrc + k0 + j*8192, AsDst + j*512);                     \
            gld_lds16(Bsrc + k0 + j*8192, BsDst + j*512);                     \
        }                                                                     \
        __syncthreads();                                                      \
        _Pragma("unroll") for (int ks = 0; ks < 2; ++ks) {                    \
            bf16x8 af[4], bfr[4];                                             \
            _Pragma("unroll") for (int m = 0; m < 4; ++m)                     \
                af[m]  = *(const bf16x8*)&As[rowA[m] + phys[ks]];             \
            _Pragma("unroll") for (int n = 0; n < 4; ++n)                     \
                bfr[n] = *(const bf16x8*)&Bs[rowB[n] + phys[ks]];             \
            _Pragma("unroll") for (int m = 0; m < 4; ++m)                     \
                _Pragma("unroll") for (int n = 0; n < 4; ++n)                 \
                    acc[m][n] = __builtin_amdgcn_mfma_f32_16x16x32_bf16(      \
                        FIRST, SECOND, acc[m][n], 0, 0, 0);                   \
        }                                                                     \
        __syncthreads();                                                      \
    }

// ---------------- QKV projection GEMM ----------------
__global__ __launch_bounds__(256) void gemm_qkv(const bf16* __restrict__ A, const bf16* __restrict__ Bw,
                                                bf16* __restrict__ Qp, bf16* __restrict__ Kp,
                                                bf16* __restrict__ Vt) {
    __shared__ bf16 As[128*64];
    __shared__ bf16 Bs[128*64];
    GEMM_PRE();
    const int part = n0 >> 10;  // 0=Q,1=K,2=V (block-uniform)
    f32x4 acc[4][4] = {};

    if (part != 2) {
        GEMM_KLOOP(af[m], bfr[n]);
        bf16* dst = (part == 0) ? Qp : Kp;
        int hh[4], dd[4];
#pragma unroll
        for (int n = 0; n < 4; ++n) {
            int rem = (n0 + wn*64 + n*16 + lm) & 1023;
            hh[n] = rem >> 6; dd[n] = rem & 63;
        }
#pragma unroll
        for (int m = 0; m < 4; ++m) {
#pragma unroll
            for (int r = 0; r < 4; ++r) {
                int gm = m0 + wm*64 + m*16 + lq*4 + r;
                int b  = gm / 480;
                int nn = gm - b*480;
#pragma unroll
                for (int n = 0; n < 4; ++n)
                    dst[((b*16 + hh[n])*480 + nn)*64 + dd[n]] = (bf16)acc[m][n][r];
            }
        }
    } else {
        GEMM_KLOOP(bfr[n], af[m]);
#pragma unroll
        for (int m = 0; m < 4; ++m) {
            int gmBase = m0 + wm*64 + m*16;
            int b  = gmBase / 480;
            int nn = gmBase - b*480 + lm;
#pragma unroll
            for (int n = 0; n < 4; ++n)
#pragma unroll
                for (int r = 0; r < 4; ++r) {
                    int rem = (n0 + wn*64 + n*16 + lq*4 + r) & 1023;
                    int h = rem >> 6, d = rem & 63;
                    Vt[((b*16 + h)*64 + d)*480 + nn] = (bf16)acc[m][n][r];
                }
        }
    }
}

// ---------------- fused attention v4 ----------------
// 2 q-subtiles per wave (32 q): ka/va LDS fragment reads amortized over 2x
// the MFMAs -> LDS read bytes per q halved. grid (3,512)=1536 blocks = 6/CU.
#define KT 96
#define KS_LD 68    // 136B rows: ka b128 phase-uniform
#define VS_LD 100   // 200B rows: va b64 hits 16 distinct banks per phase
__global__ __launch_bounds__(320) void attn(const bf16* __restrict__ Qp, const bf16* __restrict__ Kp,
                                            const bf16* __restrict__ Vt, const float* __restrict__ pe,
                                            bf16* __restrict__ O) {
    __shared__ bf16 Sm[KT*KS_LD + 64*VS_LD];   // Ks | Vs; reused as Os in epilogue
    bf16* Ks = Sm;
    bf16* Vs = Sm + KT*KS_LD;
    const int tid  = threadIdx.x;
    const int lane = tid & 63, wid = tid >> 6;
    const int bh   = blockIdx.y;
    const int b    = bh >> 4, h = bh & 15;
    const int qblk = blockIdx.x * 160;
    const int lm   = lane & 15, lq = lane >> 4;
    const int qbase = bh * (N_ * 64);

    // Q fragments as B-operand (n=q=lm, k=d=lq*8+j); 2 q-subtiles per wave
    bf16x8 qb[2][2];
#pragma unroll
    for (int t = 0; t < 2; ++t)
#pragma unroll
        for (int ks = 0; ks < 2; ++ks)
            qb[t][ks] = *(const bf16x8*)&Qp[qbase + (qblk + wid*32 + t*16 + lm)*64 + ks*32 + lq*8];
    const float* peA = pe + (qblk + wid*32      + lm)*480;
    const float* peB = pe + (qblk + wid*32 + 16 + lm)*480;

    f32x4 ot[2][4] = {};   // O^T accum per subtile: m=d (4 frags), n=q
    float lsum[2] = {0.f, 0.f};

    for (int kt = 0; kt < 5; ++kt) {
        __syncthreads();
        for (int c = tid; c < 768; c += 320) {
            int row = c >> 3, of = (c & 7) * 8;
            *(uint4*)&Ks[row*KS_LD + of] = *(const uint4*)&Kp[qbase + (kt*KT + row)*64 + of];
        }
        for (int c = tid; c < 768; c += 320) {
            int row = c / 12, of = (c % 12) * 8;
            *(uint4*)&Vs[row*VS_LD + of] = *(const uint4*)&Vt[qbase + row*480 + kt*KT + of];
        }
        __syncthreads();

        // S^T = K Q^T for both subtiles, sharing the ka fragment reads
        short4v pbA[6], pbB[6];
#pragma unroll
        for (int mf = 0; mf < 6; ++mf) {
            f32x4 sA = {}, sB = {};
#pragma unroll
            for (int ks = 0; ks < 2; ++ks) {
                bf16x8 ka = *(const bf16x8*)&Ks[(mf*16 + lm)*KS_LD + ks*32 + lq*8];
                sA = __builtin_amdgcn_mfma_f32_16x16x32_bf16(ka, qb[0][ks], sA, 0, 0, 0);
                sB = __builtin_amdgcn_mfma_f32_16x16x32_bf16(ka, qb[1][ks], sB, 0, 0, 0);
            }
            bf16x4 pA, pB;
#pragma unroll
            for (int r = 0; r < 4; ++r) {
                float eA = __expf(sA[r] * 0.125f + peA[kt*KT + mf*16 + lq*4 + r]);
                float eB = __expf(sB[r] * 0.125f + peB[kt*KT + mf*16 + lq*4 + r]);
                lsum[0] += eA; lsum[1] += eB;
                pA[r] = (bf16)eA; pB[r] = (bf16)eB;
            }
            pbA[mf] = __builtin_bit_cast(short4v, pA);
            pbB[mf] = __builtin_bit_cast(short4v, pB);
        }

        // O^T += V^T P^T via 16x16x16, sharing the va fragment reads
#pragma unroll
        for (int df = 0; df < 4; ++df)
#pragma unroll
            for (int mf = 0; mf < 6; ++mf) {
                short4v va = *(const short4v*)&Vs[(df*16 + lm)*VS_LD + mf*16 + lq*4];
                ot[0][df] = __builtin_amdgcn_mfma_f32_16x16x16bf16_1k(va, pbA[mf], ot[0][df], 0, 0, 0);
                ot[1][df] = __builtin_amdgcn_mfma_f32_16x16x16bf16_1k(va, pbB[mf], ot[1][df], 0, 0, 0);
            }
    }

    // softmax denom across the 4 lane-groups holding q=lm
#pragma unroll
    for (int t = 0; t < 2; ++t) {
        lsum[t] += __shfl_xor(lsum[t], 16);
        lsum[t] += __shfl_xor(lsum[t], 32);
    }

    // transpose O^T -> O via LDS (overlay on Ks|Vs), coalesced 16B stores
    __syncthreads();
    bf16* Os = Sm;  // [160 q][KS_LD]
#pragma unroll
    for (int t = 0; t < 2; ++t) {
        float rl = 1.f / lsum[t];
#pragma unroll
        for (int df = 0; df < 4; ++df) {
            bf16x4 v;
#pragma unroll
            for (int r = 0; r < 4; ++r) v[r] = (bf16)(ot[t][df][r] * rl);
            *(bf16x4*)&Os[(wid*32 + t*16 + lm)*KS_LD + df*16 + lq*4] = v;
        }
    }
    __syncthreads();
    for (int c = tid; c < 1280; c += 320) {
        int row = c >> 3, d0 = (c & 7) * 8;
        uint4 u = *(const uint4*)&Os[row*KS_LD + d0];
        *(uint4*)&O[(b*480 + qblk + row)*1024 + h*64 + d0] = u;
    }
}

// ---------------- output projection GEMM + bias ----------------
__global__ __launch_bounds__(256) void gemm_out(const bf16* __restrict__ A, const bf16* __restrict__ Bw,
                                                const float* __restrict__ bo, float* __restrict__ out) {
    __shared__ bf16 As[128*64];
    __shared__ bf16 Bs[128*64];
    GEMM_PRE();
    f32x4 acc[4][4] = {};
    GEMM_KLOOP(af[m], bfr[n]);
#pragma unroll
    for (int m = 0; m < 4; ++m)
#pragma unroll
        for (int n = 0; n < 4; ++n)
#pragma unroll
            for (int r = 0; r < 4; ++r) {
                int gm = m0 + wm*64 + m*16 + lq*4 + r;
                int gn = n0 + wn*64 + n*16 + lm;
                out[gm*1024 + gn] = acc[m][n][r] + bo[gn];
            }
}

// ---------------- launcher ----------------
extern "C" void kernel_launch(void* const* d_in, const int* in_sizes, int n_in,
                              void* d_out, int out_size, void* d_ws, size_t ws_size,
                              hipStream_t stream) {
    const float* q  = (const float*)d_in[0];
    const float* Wq = (const float*)d_in[1];
    const float* Wk = (const float*)d_in[2];
    const float* Wv = (const float*)d_in[3];
    const float* pe = (const float*)d_in[4];
    const float* Wo = (const float*)d_in[5];
    const float* bo = (const float*)d_in[6];
    float* out = (float*)d_out;

    char* ws = (char*)d_ws;
    bf16* Abf  = (bf16*)(ws);                         // q bf16 (M x 1024); reused as attn O buffer
    bf16* Wcat = (bf16*)(ws + 31457280);              // 3072 x 1024
    bf16* Wob  = (bf16*)(ws + 31457280 + 6291456);    // 1024 x 1024
    bf16* Qp   = (bf16*)(ws + 39845888);              // [bh][n][d]
    bf16* Kp   = (bf16*)(ws + 71303168);              // [bh][n][d]
    bf16* Vt   = (bf16*)(ws + 102760448);             // [bh][d][n]

    cvt4<<<(M_*DIM_/4 + 255)/256, 256, 0, stream>>>(q, Abf, M_*DIM_/4);
    cvtW<<<dim3(DIM_*DIM_/4/256, 4), 256, 0, stream>>>(Wq, Wk, Wv, Wo, Wcat, Wob);

    gemm_qkv<<<dim3(24, 120), 256, 0, stream>>>(Abf, Wcat, Qp, Kp, Vt);
    attn<<<dim3(3, 512), 320, 0, stream>>>(Qp, Kp, Vt, pe, Abf);
    gemm_out<<<dim3(8, 120), 256, 0, stream>>>(Abf, Wob, bo, out);
}